// Round 12
// baseline (390.887 us; speedup 1.0000x reference)
//
#include <hip/hip_runtime.h>
#include <hip/hip_bf16.h>

// ---------------- problem constants ----------------
#define N_FRAMES 2048          // T*B
#define T_STEPS  128
#define BATCH    16
#define UNITS    128
#define NORM_SCALE 11.313708498984760390f  // sqrt(128)

typedef short bf16x8 __attribute__((ext_vector_type(8)));
typedef float f32x4 __attribute__((ext_vector_type(4)));

static __device__ inline unsigned short f2bf(float f) {
    __hip_bfloat16 h = __float2bfloat16(f);
    return __builtin_bit_cast(unsigned short, h);
}

// ---------------- workspace layout (float elements) ----------------
static const size_t OFF_W1P   = 0;            // 16KB ush: conv1 MFMA weights [ky][nt][lane][8]
static const size_t OFF_W2P   = 6144;         // 64KB ush: conv2 MFMA B-frags [16][4][64][8]
static const size_t OFF_W3P   = 38912;        // 72KB ush: conv3 MFMA B-frags [9][2][4][64][8]
static const size_t OFF_FCWP  = 75776;        // ush: fc MFMA B-frags [100][32][64][8]
static const size_t OFF_HSR   = 1681408;      // 262144
static const size_t OFF_HSI   = 1943552;      // 262144
static const size_t OFF_PROJR = 2205696;      // 262144
static const size_t OFF_PROJI = 2467840;      // 262144
static const size_t OFF_H     = 2729984;      // 1048576 : fc output [2048][512] f32
static const size_t OFF_Y2    = 3778560;      // ush: y2 bf16 [2048][9][9][64]
static const size_t OFF_WRTR  = OFF_Y2;       // 16384 f32: wrec_r transposed (after conv3 consumed y2)
static const size_t OFF_WRTI  = OFF_Y2 + 16384; // 16384 f32: wrec_i transposed
static const size_t OFF_Y1    = 14395392;     // ush: y1 bf16 [2048][20][20][32]
static const size_t OFF_Y3    = OFF_Y1;       // ush: y3 bf16 [2048][3136] (reuses y1 after conv2)

// ---------------- weight permutes ----------------
__global__ void permute_w1mf(const float* __restrict__ w, unsigned short* __restrict__ o) {
    int i = blockIdx.x * 256 + threadIdx.x;      // 8192
    if (i >= 8192) return;
    int j = i & 7; int lane = (i >> 3) & 63; int nt = (i >> 9) & 1; int ky = i >> 10;
    int t = (lane >> 4) * 8 + j;
    int oc = nt * 16 + (lane & 15);
    float v = 0.f;
    if (t < 24) {
        int kx = t / 3, ic = t % 3;
        v = w[((oc * 3 + ic) * 8 + ky) * 8 + kx] * (1.0f / 255.0f);
    }
    o[i] = f2bf(v);
}
__global__ void permute_w2mf(const float* __restrict__ w, unsigned short* __restrict__ o) {
    int i = blockIdx.x * 256 + threadIdx.x;      // 32768
    if (i >= 32768) return;
    int j = i & 7; int lane = (i >> 3) & 63; int nt = (i >> 9) & 3; int kk = i >> 11;
    int ic = (lane >> 4) * 8 + j;
    int oc = nt * 16 + (lane & 15);
    int ky = kk >> 2, kx = kk & 3;
    o[i] = f2bf(w[((oc * 32 + ic) * 4 + ky) * 4 + kx]);
}
__global__ void permute_w3mf(const float* __restrict__ w, unsigned short* __restrict__ o) {
    int i = blockIdx.x * 256 + threadIdx.x;      // 36864
    if (i >= 36864) return;
    int j = i & 7; int lane = (i >> 3) & 63; int nt = (i >> 9) & 3; int c = (i >> 11) & 1; int kk = i >> 12;
    int ic = c * 32 + (lane >> 4) * 8 + j;
    int oc = nt * 16 + (lane & 15);
    int ky = kk / 3, kx = kk % 3;
    o[i] = f2bf(w[((oc * 64 + ic) * 3 + ky) * 3 + kx]);
}
__global__ void permute_fcwmf(const float* __restrict__ w, unsigned short* __restrict__ o) {
    int i = blockIdx.x * 256 + threadIdx.x;      // 1638400
    if (i >= 1638400) return;
    int jj = i & 7; int lane = (i >> 3) & 63; int ntg = (i >> 9) & 31; int kk = i >> 14;
    int k = kk * 32 + (lane >> 4) * 8 + jj;
    int n = ntg * 16 + (lane & 15);
    float v = 0.f;
    if (k < 3136) {
        int p = k >> 6, c = k & 63;
        v = w[(size_t)(c * 49 + p) * 512 + n];
    }
    o[i] = f2bf(v);
}
__global__ void permute_wrt(const float* __restrict__ wr, const float* __restrict__ wi,
                            float* __restrict__ otr, float* __restrict__ oti) {
    int i = blockIdx.x * 256 + threadIdx.x;      // 16384
    if (i >= 16384) return;
    int k = i & 127, u = i >> 7;
    otr[i] = wr[k * 128 + u];
    oti[i] = wi[k * 128 + u];
}

// ---------------- conv1 v6: MFMA implicit GEMM, bf16 output (unchanged) ----------------
__global__ __launch_bounds__(256) void conv1_kernel(const float* __restrict__ x,
                                                    const unsigned short* __restrict__ wmf,
                                                    const float* __restrict__ b,
                                                    unsigned short* __restrict__ y) {
    __shared__ unsigned short xs[11096];
    int tid = threadIdx.x;
    int blk = blockIdx.x;
    int n = blk >> 1, hb = blk & 1;

    const float4* xb4 = reinterpret_cast<const float4*>(x + (size_t)n * 21168 + hb * 40 * 252);
#pragma unroll
    for (int it = 0; it < 11; ++it) {
        int i = it * 256 + tid;
        if (i < 2772) {
            float4 v = xb4[i];
            ushort4 h;
            h.x = f2bf(v.x); h.y = f2bf(v.y); h.z = f2bf(v.z); h.w = f2bf(v.w);
            *reinterpret_cast<ushort4*>(&xs[i * 4]) = h;
        }
    }
    if (tid < 8) xs[11088 + tid] = 0;
    __syncthreads();

    int lane = tid & 63;
    int wv = tid >> 6;
    int row = lane & 15;
    int seg = lane >> 4;
    const uint4* wm = reinterpret_cast<const uint4*>(wmf);
    float b0 = b[row];
    float b1 = b[16 + row];
    int pbase = n * 400 + hb * 200;

    for (int tile = wv; tile < 13; tile += 4) {
        int p = tile * 16 + row; if (p > 199) p = 199;
        int eb = (p / 20) * 1008 + (p % 20) * 12 + seg * 8;
        f32x4 acc0 = {0.f, 0.f, 0.f, 0.f};
        f32x4 acc1 = {0.f, 0.f, 0.f, 0.f};
#pragma unroll
        for (int ky = 0; ky < 8; ++ky) {
            int ea = eb + ky * 252;
            ushort4 lo = *reinterpret_cast<const ushort4*>(&xs[ea]);
            ushort4 hi = *reinterpret_cast<const ushort4*>(&xs[ea + 4]);
            bf16x8 a = {(short)lo.x, (short)lo.y, (short)lo.z, (short)lo.w,
                        (short)hi.x, (short)hi.y, (short)hi.z, (short)hi.w};
            bf16x8 w0 = __builtin_bit_cast(bf16x8, wm[(ky * 2 + 0) * 64 + lane]);
            bf16x8 w1 = __builtin_bit_cast(bf16x8, wm[(ky * 2 + 1) * 64 + lane]);
            acc0 = __builtin_amdgcn_mfma_f32_16x16x32_bf16(a, w0, acc0, 0, 0, 0);
            acc1 = __builtin_amdgcn_mfma_f32_16x16x32_bf16(a, w1, acc1, 0, 0, 0);
        }
#pragma unroll
        for (int r = 0; r < 4; ++r) {
            int pl = tile * 16 + seg * 4 + r;
            if (pl < 200) {
                unsigned short* yp = y + ((size_t)(pbase + pl)) * 32 + row;
                yp[0]  = f2bf(fmaxf(acc0[r] + b0, 0.f));
                yp[16] = f2bf(fmaxf(acc1[r] + b1, 0.f));
            }
        }
    }
}

// ---------------- conv2 v5: MFMA implicit GEMM, bf16 output (unchanged) ----------------
__global__ __launch_bounds__(256) void conv2_kernel(const unsigned short* __restrict__ y1b,
                                                    const unsigned short* __restrict__ wt,
                                                    const float* __restrict__ b,
                                                    unsigned short* __restrict__ y2) {
    __shared__ unsigned short xs[2 * 12800];
    int tid = threadIdx.x;
    int n0 = blockIdx.x * 2;
    const uint4* xg = reinterpret_cast<const uint4*>(y1b + (size_t)n0 * 12800);
    uint4* xs4 = reinterpret_cast<uint4*>(xs);
#pragma unroll
    for (int q = 0; q < 13; ++q) {
        int i = q * 256 + tid;
        if (i < 3200) {
            uint4 v = xg[i];
            int swz = (i & ~3) | ((i & 3) ^ ((i >> 3) & 3));
            xs4[swz] = v;
        }
    }
    __syncthreads();

    int lane = tid & 63;
    int wv = tid >> 6;
    int img = wv >> 1;
    int tbase = (wv & 1) * 3;
    int row = lane & 15, seg = lane >> 4;
    int imgb = img * 1600;

    int ibase[3];
#pragma unroll
    for (int t = 0; t < 3; ++t) {
        int p = (tbase + t) * 16 + row; if (p > 80) p = 80;
        ibase[t] = (p / 9) * 40 + (p % 9) * 2;
    }
    const uint4* B4 = reinterpret_cast<const uint4*>(wt);
    f32x4 acc[3][4];
#pragma unroll
    for (int t = 0; t < 3; ++t)
#pragma unroll
        for (int nt = 0; nt < 4; ++nt) acc[t][nt] = (f32x4){0.f, 0.f, 0.f, 0.f};

#pragma unroll 1
    for (int kk = 0; kk < 16; ++kk) {
        int ky = kk >> 2, kx = kk & 3;
        int koff = ky * 20 + kx;
        bf16x8 bb[4];
#pragma unroll
        for (int nt = 0; nt < 4; ++nt)
            bb[nt] = __builtin_bit_cast(bf16x8, B4[(kk * 4 + nt) * 64 + lane]);
        bf16x8 a[3];
#pragma unroll
        for (int t = 0; t < 3; ++t) {
            int ipx = ibase[t] + koff;
            int a16 = imgb + ipx * 4 + (seg ^ ((ipx >> 1) & 3));
            a[t] = __builtin_bit_cast(bf16x8, *reinterpret_cast<const uint4*>(&xs[a16 * 8]));
        }
#pragma unroll
        for (int t = 0; t < 3; ++t)
#pragma unroll
            for (int nt = 0; nt < 4; ++nt)
                acc[t][nt] = __builtin_amdgcn_mfma_f32_16x16x32_bf16(a[t], bb[nt], acc[t][nt], 0, 0, 0);
    }

#pragma unroll
    for (int nt = 0; nt < 4; ++nt) {
        int c = nt * 16 + row;
        float bc = b[c];
#pragma unroll
        for (int t = 0; t < 3; ++t)
#pragma unroll
            for (int r = 0; r < 4; ++r) {
                int p = (tbase + t) * 16 + seg * 4 + r;
                if (p < 81)
                    y2[((size_t)(n0 + img) * 81 + p) * 64 + c] = f2bf(fmaxf(acc[t][nt][r] + bc, 0.f));
            }
    }
}

// ---------------- conv3 v5: MFMA implicit GEMM (unchanged) ----------------
__global__ __launch_bounds__(256) void conv3_kernel(const unsigned short* __restrict__ y2b,
                                                    const unsigned short* __restrict__ wt,
                                                    const float* __restrict__ b,
                                                    unsigned short* __restrict__ y3) {
    __shared__ unsigned short xs[2 * 5184];
    int tid = threadIdx.x;
    int n0 = blockIdx.x * 2;
    const uint4* xg = reinterpret_cast<const uint4*>(y2b + (size_t)n0 * 5184);
    uint4* xs4 = reinterpret_cast<uint4*>(xs);
#pragma unroll
    for (int q = 0; q < 6; ++q) {
        int i = q * 256 + tid;
        if (i < 1296) {
            uint4 v = xg[i];
            int px = i >> 3, qq = i & 7;
            xs4[px * 8 + (qq ^ (px & 7))] = v;
        }
    }
    __syncthreads();

    int lane = tid & 63;
    int wv = tid >> 6;
    int img = wv >> 1;
    int tbase = (wv & 1) * 2;
    int row = lane & 15, seg = lane >> 4;

    int ibase[2];
#pragma unroll
    for (int t = 0; t < 2; ++t) {
        int p = (tbase + t) * 16 + row; if (p > 48) p = 48;
        ibase[t] = img * 81 + (p / 7) * 9 + (p % 7);
    }
    const uint4* B4 = reinterpret_cast<const uint4*>(wt);
    f32x4 acc[2][4];
#pragma unroll
    for (int t = 0; t < 2; ++t)
#pragma unroll
        for (int nt = 0; nt < 4; ++nt) acc[t][nt] = (f32x4){0.f, 0.f, 0.f, 0.f};

#pragma unroll 1
    for (int kk = 0; kk < 9; ++kk) {
        int ky = kk / 3, kx = kk % 3;
        int koff = ky * 9 + kx;
#pragma unroll
        for (int c = 0; c < 2; ++c) {
            bf16x8 bb[4];
#pragma unroll
            for (int nt = 0; nt < 4; ++nt)
                bb[nt] = __builtin_bit_cast(bf16x8, B4[((kk * 2 + c) * 4 + nt) * 64 + lane]);
            bf16x8 a[2];
#pragma unroll
            for (int t = 0; t < 2; ++t) {
                int px = ibase[t] + koff;
                int u16 = px * 8 + ((c * 4 + seg) ^ (px & 7));
                a[t] = __builtin_bit_cast(bf16x8, *reinterpret_cast<const uint4*>(&xs[u16 * 8]));
            }
#pragma unroll
            for (int t = 0; t < 2; ++t)
#pragma unroll
                for (int nt = 0; nt < 4; ++nt)
                    acc[t][nt] = __builtin_amdgcn_mfma_f32_16x16x32_bf16(a[t], bb[nt], acc[t][nt], 0, 0, 0);
        }
    }

#pragma unroll
    for (int nt = 0; nt < 4; ++nt) {
        int c = nt * 16 + row;
        float bc = b[c];
#pragma unroll
        for (int t = 0; t < 2; ++t)
#pragma unroll
            for (int r = 0; r < 4; ++r) {
                int p = (tbase + t) * 16 + seg * 4 + r;
                if (p < 49)
                    y3[(size_t)(n0 + img) * 3136 + p * 64 + c] = f2bf(fmaxf(acc[t][nt][r] + bc, 0.f));
            }
    }
}

// ---------------- FC v2: bf16 MFMA (unchanged) ----------------
__global__ __launch_bounds__(256) void fc_kernel(const unsigned short* __restrict__ A,
                                                 const unsigned short* __restrict__ Bt,
                                                 const float* __restrict__ bias,
                                                 float* __restrict__ C) {
    __shared__ float Cs[64][65];
    int tid = threadIdx.x;
    int lane = tid & 63;
    int wv = tid >> 6;
    int bm = blockIdx.x & 31;
    int bn = blockIdx.x >> 5;
    int row = lane & 15, seg = lane >> 4;

    const uint4* B4 = reinterpret_cast<const uint4*>(Bt);
    f32x4 acc[4][4];
#pragma unroll
    for (int mf = 0; mf < 4; ++mf)
#pragma unroll
        for (int nf = 0; nf < 4; ++nf) acc[mf][nf] = (f32x4){0.f, 0.f, 0.f, 0.f};

    const unsigned short* Abase = A + (size_t)(bm * 64 + row) * 3136 + seg * 8;

#pragma unroll 1
    for (int kk = wv; kk < 100; kk += 4) {
        bf16x8 a[4], bb[4];
#pragma unroll
        for (int mf = 0; mf < 4; ++mf)
            a[mf] = __builtin_bit_cast(bf16x8,
                *reinterpret_cast<const uint4*>(Abase + (size_t)mf * 16 * 3136 + kk * 32));
#pragma unroll
        for (int nf = 0; nf < 4; ++nf)
            bb[nf] = __builtin_bit_cast(bf16x8, B4[(kk * 32 + bn * 4 + nf) * 64 + lane]);
#pragma unroll
        for (int mf = 0; mf < 4; ++mf)
#pragma unroll
            for (int nf = 0; nf < 4; ++nf)
                acc[mf][nf] = __builtin_amdgcn_mfma_f32_16x16x32_bf16(a[mf], bb[nf], acc[mf][nf], 0, 0, 0);
    }

#pragma unroll 1
    for (int w = 0; w < 4; ++w) {
        if (wv == w) {
#pragma unroll
            for (int mf = 0; mf < 4; ++mf)
#pragma unroll
                for (int nf = 0; nf < 4; ++nf)
#pragma unroll
                    for (int r = 0; r < 4; ++r) {
                        int rr = mf * 16 + seg * 4 + r;
                        int cc = nf * 16 + row;
                        if (w == 0) Cs[rr][cc] = acc[mf][nf][r];
                        else        Cs[rr][cc] += acc[mf][nf][r];
                    }
        }
        __syncthreads();
    }

    int r = tid >> 2, cq = (tid & 3) * 16;
#pragma unroll
    for (int q = 0; q < 4; ++q) {
        int c0 = cq + q * 4;
        float4 v = *reinterpret_cast<float4*>(&Cs[r][c0]);
        float4 bv = *reinterpret_cast<const float4*>(&bias[bn * 64 + c0]);
        v.x = fmaxf(v.x + bv.x, 0.f);
        v.y = fmaxf(v.y + bv.y, 0.f);
        v.z = fmaxf(v.z + bv.z, 0.f);
        v.w = fmaxf(v.w + bv.w, 0.f);
        *reinterpret_cast<float4*>(&C[(size_t)(bm * 64 + r) * 512 + bn * 64 + c0]) = v;
    }
}

// ---------------- proj (unchanged) ----------------
__global__ __launch_bounds__(256) void proj_kernel(const float* __restrict__ h,
                                                   const float* __restrict__ winr,
                                                   const float* __restrict__ wini,
                                                   float* __restrict__ pr,
                                                   float* __restrict__ pi) {
    int idx = blockIdx.x * 256 + threadIdx.x;
    int u = idx & 127;
    int n0 = (idx >> 7) * 8;
    float ar[8] = {}, ai[8] = {};
    for (int k = 0; k < 512; ++k) {
        float wrv = winr[k * 128 + u], wiv = wini[k * 128 + u];
#pragma unroll
        for (int g = 0; g < 8; ++g) {
            float hv = h[(size_t)(n0 + g) * 512 + k];
            ar[g] = fmaf(hv, wrv, ar[g]);
            ai[g] = fmaf(hv, wiv, ai[g]);
        }
    }
#pragma unroll
    for (int g = 0; g < 8; ++g) {
        pr[(size_t)(n0 + g) * 128 + u] = ar[g];
        pi[(size_t)(n0 + g) * 128 + u] = ai[g];
    }
}

// ---------------- RNN scan v3: named-register weights, prefetch, lean reduce ----------------
#define CSTEP(Wr, Wi, q, AR, AI) {                                        \
    float4 sr_ = sR4[q], si_ = sI4[q];                                    \
    AR = fmaf(sr_.x, Wr.x, AR); AR = fmaf(-si_.x, Wi.x, AR);              \
    AI = fmaf(sr_.x, Wi.x, AI); AI = fmaf(si_.x, Wr.x, AI);               \
    AR = fmaf(sr_.y, Wr.y, AR); AR = fmaf(-si_.y, Wi.y, AR);              \
    AI = fmaf(sr_.y, Wi.y, AI); AI = fmaf(si_.y, Wr.y, AI);               \
    AR = fmaf(sr_.z, Wr.z, AR); AR = fmaf(-si_.z, Wi.z, AR);              \
    AI = fmaf(sr_.z, Wi.z, AI); AI = fmaf(si_.z, Wr.z, AI);               \
    AR = fmaf(sr_.w, Wr.w, AR); AR = fmaf(-si_.w, Wi.w, AR);              \
    AI = fmaf(sr_.w, Wi.w, AI); AI = fmaf(si_.w, Wr.w, AI); }

__global__ __launch_bounds__(512, 2) void scan_kernel(const float* __restrict__ done,
                                                      const float* __restrict__ sr0,
                                                      const float* __restrict__ si0,
                                                      const float* __restrict__ wrtR,
                                                      const float* __restrict__ wrtI,
                                                      const float* __restrict__ pr,
                                                      const float* __restrict__ pi,
                                                      float* __restrict__ hsr,
                                                      float* __restrict__ hsi) {
    int b = blockIdx.x;
    int tid = threadIdx.x;
    int u = tid & 127;
    int s = tid >> 7;
    int w = tid >> 6;

    const float4* wr4 = reinterpret_cast<const float4*>(wrtR + u * 128 + s * 32);
    const float4* wi4 = reinterpret_cast<const float4*>(wrtI + u * 128 + s * 32);
    float4 Wr0 = wr4[0], Wr1 = wr4[1], Wr2 = wr4[2], Wr3 = wr4[3];
    float4 Wr4_ = wr4[4], Wr5 = wr4[5], Wr6 = wr4[6], Wr7 = wr4[7];
    float4 Wi0 = wi4[0], Wi1 = wi4[1], Wi2 = wi4[2], Wi3 = wi4[3];
    float4 Wi4_ = wi4[4], Wi5 = wi4[5], Wi6 = wi4[6], Wi7 = wi4[7];

    __shared__ __align__(16) float stR[128], stI[128];
    __shared__ float parR[4][128], parI[4][128];
    __shared__ float redw[2];

    // prologue: state init + wrec column sums (done-blend linear fold)
    if (s == 0) { stR[u] = sr0[b * 128 + u]; stI[u] = si0[b * 128 + u]; }
    float cr = ((Wr0.x + Wr0.y + Wr0.z + Wr0.w) + (Wr1.x + Wr1.y + Wr1.z + Wr1.w))
             + ((Wr2.x + Wr2.y + Wr2.z + Wr2.w) + (Wr3.x + Wr3.y + Wr3.z + Wr3.w))
             + ((Wr4_.x + Wr4_.y + Wr4_.z + Wr4_.w) + (Wr5.x + Wr5.y + Wr5.z + Wr5.w))
             + ((Wr6.x + Wr6.y + Wr6.z + Wr6.w) + (Wr7.x + Wr7.y + Wr7.z + Wr7.w));
    float ci = ((Wi0.x + Wi0.y + Wi0.z + Wi0.w) + (Wi1.x + Wi1.y + Wi1.z + Wi1.w))
             + ((Wi2.x + Wi2.y + Wi2.z + Wi2.w) + (Wi3.x + Wi3.y + Wi3.z + Wi3.w))
             + ((Wi4_.x + Wi4_.y + Wi4_.z + Wi4_.w) + (Wi5.x + Wi5.y + Wi5.z + Wi5.w))
             + ((Wi6.x + Wi6.y + Wi6.z + Wi6.w) + (Wi7.x + Wi7.y + Wi7.z + Wi7.w));
    parR[s][u] = cr; parI[s][u] = ci;
    __syncthreads();
    float SWr = parR[0][u] + parR[1][u] + parR[2][u] + parR[3][u];
    float SWi = parI[0][u] + parI[1][u] + parI[2][u] + parI[3][u];
    __syncthreads();

    // prefetch t=0
    float prr = pr[b * 128 + u];
    float pri = pi[b * 128 + u];
    float d = done[b];

    for (int t = 0; t < T_STEPS; ++t) {
        // issue prefetch for t+1 (independent of state -> hides under matvec)
        float nprr = 0.f, npri = 0.f, nd = 0.f;
        if (t + 1 < T_STEPS) {
            int np2 = ((t + 1) * BATCH + b) * 128 + u;
            nprr = pr[np2]; npri = pi[np2]; nd = done[(t + 1) * BATCH + b];
        }
        float r = 1.f - d;

        const float4* sR4 = reinterpret_cast<const float4*>(&stR[s * 32]);
        const float4* sI4 = reinterpret_cast<const float4*>(&stI[s * 32]);
        float ar0 = 0.f, ar1 = 0.f, ai0 = 0.f, ai1 = 0.f;
        CSTEP(Wr0, Wi0, 0, ar0, ai0)
        CSTEP(Wr1, Wi1, 1, ar1, ai1)
        CSTEP(Wr2, Wi2, 2, ar0, ai0)
        CSTEP(Wr3, Wi3, 3, ar1, ai1)
        CSTEP(Wr4_, Wi4_, 4, ar0, ai0)
        CSTEP(Wr5, Wi5, 5, ar1, ai1)
        CSTEP(Wr6, Wi6, 6, ar0, ai0)
        CSTEP(Wr7, Wi7, 7, ar1, ai1)
        parR[s][u] = ar0 + ar1;
        parI[s][u] = ai0 + ai1;
        __syncthreads();                                 // bar 1

        if (s == 0) {                                    // waves 0-1 only
            float tr_ = (parR[0][u] + parR[1][u]) + (parR[2][u] + parR[3][u]);
            float ti_ = (parI[0][u] + parI[1][u]) + (parI[2][u] + parI[3][u]);
            float pre_r = fmaf(r, tr_, fmaf(d, SWr, prr));
            float pre_i = fmaf(r, ti_, fmaf(d, SWi, pri));
            float sq = fmaf(pre_r, pre_r, pre_i * pre_i);
#pragma unroll
            for (int off = 32; off; off >>= 1) sq += __shfl_xor(sq, off);
            if ((tid & 63) == 0) redw[w] = sq;
            // stash pre in LDS-free registers across bar2 via parR slot reuse is
            // unnecessary: recompute-free path below keeps pre_r/pre_i live.
            parR[0][u] = pre_r;                          // reuse parR row 0 as pre store
            parI[0][u] = pre_i;
        }
        __syncthreads();                                 // bar 2
        if (s == 0) {
            float norm = redw[0] + redw[1];
            float scale = NORM_SCALE * rsqrtf(norm);
            float nr = parR[0][u] * scale, ni = parI[0][u] * scale;
            stR[u] = nr; stI[u] = ni;
            int np = (t * BATCH + b) * 128 + u;
            hsr[np] = nr; hsi[np] = ni;
        }
        __syncthreads();                                 // bar 3
        prr = nprr; pri = npri; d = nd;
    }
}

// ---------------- heads (unchanged) ----------------
__global__ void heads_kernel(const float* __restrict__ hsr, const float* __restrict__ hsi,
                             const float* __restrict__ aw, const float* __restrict__ ab,
                             const float* __restrict__ cw, const float* __restrict__ cb,
                             float* __restrict__ out) {
    int idx = blockIdx.x * 256 + threadIdx.x;
    if (idx >= N_FRAMES * 7) return;
    int j = idx % 7;
    int n = idx / 7;
    float acc;
    if (j < 6) {
        acc = ab[j];
        for (int k = 0; k < 128; ++k) acc = fmaf(hsr[n * 128 + k], aw[k * 6 + j], acc);
        for (int k = 0; k < 128; ++k) acc = fmaf(hsi[n * 128 + k], aw[(128 + k) * 6 + j], acc);
    } else {
        acc = cb[0];
        for (int k = 0; k < 128; ++k) acc = fmaf(hsr[n * 128 + k], cw[k], acc);
        for (int k = 0; k < 128; ++k) acc = fmaf(hsi[n * 128 + k], cw[128 + k], acc);
    }
    out[idx] = acc;
}

// ---------------- launch ----------------
extern "C" void kernel_launch(void* const* d_in, const int* in_sizes, int n_in,
                              void* d_out, int out_size, void* d_ws, size_t ws_size,
                              hipStream_t stream) {
    const float* x        = (const float*)d_in[0];
    const float* done     = (const float*)d_in[1];
    const float* sr0      = (const float*)d_in[2];
    const float* si0      = (const float*)d_in[3];
    const float* conv1_w  = (const float*)d_in[4];
    const float* conv1_b  = (const float*)d_in[5];
    const float* conv2_w  = (const float*)d_in[6];
    const float* conv2_b  = (const float*)d_in[7];
    const float* conv3_w  = (const float*)d_in[8];
    const float* conv3_b  = (const float*)d_in[9];
    const float* fc_w     = (const float*)d_in[10];
    const float* fc_b     = (const float*)d_in[11];
    const float* win_r    = (const float*)d_in[12];
    const float* win_i    = (const float*)d_in[13];
    const float* wrec_r   = (const float*)d_in[14];
    const float* wrec_i   = (const float*)d_in[15];
    const float* actor_w  = (const float*)d_in[16];
    const float* actor_b  = (const float*)d_in[17];
    const float* critic_w = (const float*)d_in[18];
    const float* critic_b = (const float*)d_in[19];

    float* ws = (float*)d_ws;
    unsigned short* w1mf = (unsigned short*)(ws + OFF_W1P);
    unsigned short* w2mf = (unsigned short*)(ws + OFF_W2P);
    unsigned short* w3mf = (unsigned short*)(ws + OFF_W3P);
    unsigned short* fcb = (unsigned short*)(ws + OFF_FCWP);
    float* hsr  = ws + OFF_HSR;
    float* hsi  = ws + OFF_HSI;
    float* prj  = ws + OFF_PROJR;
    float* pij  = ws + OFF_PROJI;
    float* h    = ws + OFF_H;
    unsigned short* y2b = (unsigned short*)(ws + OFF_Y2);
    float* wrtR = ws + OFF_WRTR;
    float* wrtI = ws + OFF_WRTI;
    unsigned short* y1b = (unsigned short*)(ws + OFF_Y1);
    unsigned short* y3b = (unsigned short*)(ws + OFF_Y3);
    float* outp = (float*)d_out;

    hipLaunchKernelGGL(permute_w1mf, dim3(32), dim3(256), 0, stream, conv1_w, w1mf);
    hipLaunchKernelGGL(permute_w2mf, dim3(128), dim3(256), 0, stream, conv2_w, w2mf);
    hipLaunchKernelGGL(permute_w3mf, dim3(144), dim3(256), 0, stream, conv3_w, w3mf);
    hipLaunchKernelGGL(permute_fcwmf, dim3(6400), dim3(256), 0, stream, fc_w, fcb);

    hipLaunchKernelGGL(conv1_kernel, dim3(4096), dim3(256), 0, stream, x, w1mf, conv1_b, y1b);
    hipLaunchKernelGGL(conv2_kernel, dim3(1024), dim3(256), 0, stream, y1b, w2mf, conv2_b, y2b);
    hipLaunchKernelGGL(conv3_kernel, dim3(1024), dim3(256), 0, stream, y2b, w3mf, conv3_b, y3b);
    // y2 consumed; its space now holds the transposed recurrent weights
    hipLaunchKernelGGL(permute_wrt, dim3(64), dim3(256), 0, stream, wrec_r, wrec_i, wrtR, wrtI);
    hipLaunchKernelGGL(fc_kernel, dim3(256), dim3(256), 0, stream, y3b, fcb, fc_b, h);
    hipLaunchKernelGGL(proj_kernel, dim3(128), dim3(256), 0, stream, h, win_r, win_i, prj, pij);
    hipLaunchKernelGGL(scan_kernel, dim3(16), dim3(512), 0, stream,
                       done, sr0, si0, wrtR, wrtI, prj, pij, hsr, hsi);
    hipLaunchKernelGGL(heads_kernel, dim3(56), dim3(256), 0, stream,
                       hsr, hsi, actor_w, actor_b, critic_w, critic_b, outp);
}